// Round 14
// baseline (140.863 us; speedup 1.0000x reference)
//
#include <hip/hip_runtime.h>
#include <hip/hip_bf16.h>

typedef __attribute__((ext_vector_type(8))) short bf16x8;
typedef __attribute__((ext_vector_type(4))) short bf16x4;
typedef __attribute__((ext_vector_type(4))) float f32x4;
typedef __attribute__((ext_vector_type(2))) unsigned int u32x2;

__device__ __forceinline__ void gload_lds16(const void* g, void* l) {
    __builtin_amdgcn_global_load_lds(
        (const __attribute__((address_space(1))) unsigned int*)g,
        (__attribute__((address_space(3))) unsigned int*)l, 16, 0, 0);
}

__device__ __forceinline__ unsigned int pk2(float x, float y) {
    union { __hip_bfloat16 h[2]; unsigned int u; } z;
    z.h[0] = __float2bfloat16(x); z.h[1] = __float2bfloat16(y);
    return z.u;
}

// 16x16x16 bf16 MFMA (HW-verified round 6)
__device__ __forceinline__ f32x4 mfma_16x16x16(bf16x4 a, bf16x4 b, f32x4 c) {
#if __has_builtin(__builtin_amdgcn_mfma_f32_16x16x16bf16_1k)
    return __builtin_amdgcn_mfma_f32_16x16x16bf16_1k(a, b, c, 0, 0, 0);
#else
    f32x4 d = c;
    asm volatile("v_mfma_f32_16x16x16_bf16 %0, %1, %2, %0" : "+v"(d) : "v"(a), "v"(b));
    return d;
#endif
}

// ---------------- fp32 -> bf16 elementwise convert (8 elems/thread) ----------------
__global__ void k_cvt_bf16(const float* __restrict__ x, __hip_bfloat16* __restrict__ o, int n8) {
    int i = blockIdx.x * 256 + threadIdx.x;
    if (i >= n8) return;
    const float4* xp = (const float4*)(x + (size_t)i * 8);
    float4 a = xp[0], b = xp[1];
    union { __hip_bfloat16 h[8]; uint4 u; } tu;
    tu.h[0] = __float2bfloat16(a.x); tu.h[1] = __float2bfloat16(a.y);
    tu.h[2] = __float2bfloat16(a.z); tu.h[3] = __float2bfloat16(a.w);
    tu.h[4] = __float2bfloat16(b.x); tu.h[5] = __float2bfloat16(b.y);
    tu.h[6] = __float2bfloat16(b.z); tu.h[7] = __float2bfloat16(b.w);
    *(uint4*)(o + (size_t)i * 8) = tu.u;
}

// ---- transpose fp32 [K][N] -> bf16 [N][K]; z in {0,1,2}: Wq/Wk/Wv (K=1152); z=3: Wp (K=1024) ----
__global__ void k_tr4(const float* __restrict__ s0, const float* __restrict__ s1,
                      const float* __restrict__ s2, const float* __restrict__ s3,
                      __hip_bfloat16* __restrict__ dqkv, __hip_bfloat16* __restrict__ dp) {
    __shared__ float tile[32][33];
    const int z = blockIdx.z;
    const int K = (z == 3) ? 1024 : 1152;
    const int N = 1024;
    int n0 = blockIdx.x * 32, k0 = blockIdx.y * 32;
    if (k0 >= K) return;
    const float* src = (z == 0) ? s0 : ((z == 1) ? s1 : ((z == 2) ? s2 : s3));
    __hip_bfloat16* d = (z == 3) ? dp : (dqkv + (size_t)z * N * 1152);
    int tx = threadIdx.x & 31, ty = threadIdx.x >> 5;
#pragma unroll
    for (int i = 0; i < 4; i++)
        tile[ty + i * 8][tx] = src[(size_t)(k0 + ty + i * 8) * N + n0 + tx];
    __syncthreads();
#pragma unroll
    for (int i = 0; i < 4; i++)
        d[(size_t)(n0 + ty + i * 8) * K + k0 + tx] = __float2bfloat16(tile[tx][ty + i * 8]);
}

// ---------------- QKV GEMM: 128x64 tile (GEMM1-proven geometry), 1536 blocks = 6/CU ----------------
// V path (n0>=2048): in-LDS [64n][128m] transpose epilogue, coalesced 16B stores.
#define QSCALE 0.18033688011111204f  /* (1/8) * log2(e) */

__global__ __launch_bounds__(256, 4) void k_gemmQKV(
    const __hip_bfloat16* __restrict__ A, const __hip_bfloat16* __restrict__ Bt, int K,
    const float* __restrict__ b0, const float* __restrict__ b1, const float* __restrict__ b2,
    __hip_bfloat16* __restrict__ qb, __hip_bfloat16* __restrict__ kb, __hip_bfloat16* __restrict__ vb)
{
    __shared__ __align__(16) __hip_bfloat16 Sh[12288];  // As [128][64] 16KB + Bs [64][64] 8KB
    __hip_bfloat16* As = Sh;
    __hip_bfloat16* Bs = Sh + 8192;
    const int t = threadIdx.x;
    const int lane = t & 63, w = t >> 6;
    const int wr = w >> 1, wc = w & 1;
    const int r16 = lane & 15, kg = lane >> 4;
    const int m0 = blockIdx.x * 128, n0 = blockIdx.y * 64;
    f32x4 acc[4][2] = {};
    const int ksteps = K >> 6;
    for (int kt = 0; kt < ksteps; ++kt) {
        if (kt) __syncthreads();
        const int ks = kt * 64;
#pragma unroll
        for (int i = 0; i < 4; i++) {
            int ci = i * 256 + t;
            int row = ci >> 3, kc = (ci & 7) * 8;
            gload_lds16(A + (size_t)(m0 + row) * K + ks + kc, As + ci * 8);
        }
#pragma unroll
        for (int i = 0; i < 2; i++) {
            int ci = i * 256 + t;
            int row = ci >> 3, kc = (ci & 7) * 8;
            gload_lds16(Bt + (size_t)(n0 + row) * K + ks + kc, Bs + ci * 8);
        }
        __syncthreads();
#pragma unroll
        for (int c = 0; c < 2; c++) {
            bf16x8 af[4], bfr[2];
#pragma unroll
            for (int mi = 0; mi < 4; mi++)
                af[mi] = *(const bf16x8*)(As + (wr * 64 + mi * 16 + r16) * 64 + c * 32 + kg * 8);
#pragma unroll
            for (int ni = 0; ni < 2; ni++)
                bfr[ni] = *(const bf16x8*)(Bs + (wc * 32 + ni * 16 + r16) * 64 + c * 32 + kg * 8);
#pragma unroll
            for (int mi = 0; mi < 4; mi++)
#pragma unroll
                for (int ni = 0; ni < 2; ni++)
                    acc[mi][ni] = __builtin_amdgcn_mfma_f32_16x16x32_bf16(af[mi], bfr[ni], acc[mi][ni], 0, 0, 0);
        }
    }
    if (n0 >= 2048) {
        // ---- V path: [64n][128m] transpose through LDS, coalesced 16B stores ----
        __syncthreads();  // all waves done reading As/Bs
#pragma unroll
        for (int mi = 0; mi < 4; mi++) {
#pragma unroll
            for (int ni = 0; ni < 2; ni++) {
                const int nl2 = wc * 32 + ni * 16 + r16;          // local n (0..63)
                const int mb = wr * 64 + mi * 16 + kg * 4;        // local m base (mult of 4)
                const int r = n0 - 2048 + nl2;
                const float bias = b2[r];
                u32x2 pk;
                pk[0] = pk2(acc[mi][ni][0] + bias, acc[mi][ni][1] + bias);
                pk[1] = pk2(acc[mi][ni][2] + bias, acc[mi][ni][3] + bias);
                *(u32x2*)(Sh + nl2 * 128 + (mb ^ ((nl2 & 7) << 3))) = pk;
            }
        }
        __syncthreads();
#pragma unroll
        for (int pass = 0; pass < 4; ++pass) {
            const int ci = pass * 256 + t;      // 0..1023
            const int nl2 = ci >> 4;            // 0..63
            const int ms = (ci & 15) * 8;       // 0..120
            bf16x8 v = *(const bf16x8*)(Sh + nl2 * 128 + (ms ^ ((nl2 & 7) << 3)));
            const int r = n0 - 2048 + nl2;
            const int hh = r >> 6, dd = r & 63;
            const int m = m0 + ms;
            const int bb = m >> 11, tt = m & 2047;
            *(bf16x8*)(vb + ((size_t)(bb * 16 + hh) * 64 + dd) * 2048 + tt) = v;
        }
        return;
    }
#pragma unroll
    for (int mi = 0; mi < 4; mi++) {
#pragma unroll
        for (int ni = 0; ni < 2; ni++) {
#pragma unroll
            for (int j = 0; j < 4; j++) {
                int m = m0 + wr * 64 + mi * 16 + kg * 4 + j;
                int n = n0 + wc * 32 + ni * 16 + r16;
                float val = acc[mi][ni][j];
                int r = n & 1023;
                int hh = r >> 6, dd = r & 63;
                int bb = m >> 11, tt = m & 2047;
                if (n < 1024) {
                    val = (val + b0[r]) * QSCALE;
                    qb[((size_t)(bb * 16 + hh) * 2048 + tt) * 64 + dd] = __float2bfloat16(val);
                } else {
                    val += b1[r];
                    kb[((size_t)(bb * 16 + hh) * 2048 + tt) * 64 + dd] = __float2bfloat16(val);
                }
            }
        }
    }
}

// ---------------- proj GEMM: 128x64 tile, 512 blocks (round-12 proven) ----------------
__global__ __launch_bounds__(256, 4) void k_gemmP(
    const __hip_bfloat16* __restrict__ A, const __hip_bfloat16* __restrict__ Bt,
    int N, int K, const float* __restrict__ bias, float* __restrict__ outp)
{
    __shared__ __align__(16) __hip_bfloat16 As[128 * 64];
    __shared__ __align__(16) __hip_bfloat16 Bs[64 * 64];
    const int t = threadIdx.x;
    const int lane = t & 63, w = t >> 6;
    const int wr = w >> 1, wc = w & 1;
    const int r16 = lane & 15, kg = lane >> 4;
    const int m0 = blockIdx.x * 128, n0 = blockIdx.y * 64;
    f32x4 acc[4][2] = {};
    const int ksteps = K >> 6;
    for (int kt = 0; kt < ksteps; ++kt) {
        if (kt) __syncthreads();
        const int ks = kt * 64;
#pragma unroll
        for (int i = 0; i < 4; i++) {
            int ci = i * 256 + t;
            int row = ci >> 3, kc = (ci & 7) * 8;
            gload_lds16(A + (size_t)(m0 + row) * K + ks + kc, As + ci * 8);
        }
#pragma unroll
        for (int i = 0; i < 2; i++) {
            int ci = i * 256 + t;
            int row = ci >> 3, kc = (ci & 7) * 8;
            gload_lds16(Bt + (size_t)(n0 + row) * K + ks + kc, Bs + ci * 8);
        }
        __syncthreads();
#pragma unroll
        for (int c = 0; c < 2; c++) {
            bf16x8 af[4], bfr[2];
#pragma unroll
            for (int mi = 0; mi < 4; mi++)
                af[mi] = *(const bf16x8*)(As + (wr * 64 + mi * 16 + r16) * 64 + c * 32 + kg * 8);
#pragma unroll
            for (int ni = 0; ni < 2; ni++)
                bfr[ni] = *(const bf16x8*)(Bs + (wc * 32 + ni * 16 + r16) * 64 + c * 32 + kg * 8);
#pragma unroll
            for (int mi = 0; mi < 4; mi++)
#pragma unroll
                for (int ni = 0; ni < 2; ni++)
                    acc[mi][ni] = __builtin_amdgcn_mfma_f32_16x16x32_bf16(af[mi], bfr[ni], acc[mi][ni], 0, 0, 0);
        }
    }
#pragma unroll
    for (int mi = 0; mi < 4; mi++)
#pragma unroll
        for (int ni = 0; ni < 2; ni++)
#pragma unroll
            for (int j = 0; j < 4; j++) {
                int m = m0 + wr * 64 + mi * 16 + kg * 4 + j;
                int n = n0 + wc * 32 + ni * 16 + r16;
                outp[(size_t)m * N + n] = acc[mi][ni][j] + bias[n];
            }
}

// ---------------- flash attention (round-12 proven): v6 core + bh->XCD remap ----------------
__global__ __launch_bounds__(256, 4) void k_attn(
    const __hip_bfloat16* __restrict__ qbuf,
    const __hip_bfloat16* __restrict__ kbuf,
    const __hip_bfloat16* __restrict__ vtbuf,
    __hip_bfloat16* __restrict__ y)
{
    __shared__ __align__(16) __hip_bfloat16 Kl[2][64 * 64];
    __shared__ __align__(16) __hip_bfloat16 Vl[2][64 * 64];
    const int t = threadIdx.x, lane = t & 63, w = t >> 6;
    const int r16 = lane & 15, kg = lane >> 4;
    const int g = blockIdx.x;
    const int xcd = g & 7, idx = g >> 3;
    const int j4 = idx >> 5, rr = idx & 31;
    const int bh = xcd * 4 + j4;
    const int qt = (j4 & 1) ? rr : 31 - rr;
    const int swr = (r16 & 7) << 3;
    const int q0 = qt * 64 + w * 16;
    const __hip_bfloat16* qp = qbuf + ((size_t)bh * 2048 + q0) * 64;
    bf16x8 qf0 = *(const bf16x8*)(qp + r16 * 64 + kg * 8);
    bf16x8 qf1 = *(const bf16x8*)(qp + r16 * 64 + 32 + kg * 8);
    f32x4 O[4] = {};
    float m_s = -3.0e38f, l_s = 0.f;
    const __hip_bfloat16* kb = kbuf + (size_t)bh * 2048 * 64;
    const __hip_bfloat16* vb = vtbuf + (size_t)bh * 64 * 2048;

    const int ci0 = t, ci1 = 256 + t;
    const int kr0 = ci0 >> 3, sc0 = ((ci0 & 7) * 8) ^ ((kr0 & 7) << 3);
    const int kr1 = ci1 >> 3, sc1 = ((ci1 & 7) * 8) ^ ((kr1 & 7) << 3);

    gload_lds16(kb + (size_t)kr0 * 64 + sc0, &Kl[0][ci0 * 8]);
    gload_lds16(kb + (size_t)kr1 * 64 + sc1, &Kl[0][ci1 * 8]);
    gload_lds16(vb + (size_t)kr0 * 2048 + sc0, &Vl[0][ci0 * 8]);
    gload_lds16(vb + (size_t)kr1 * 2048 + sc1, &Vl[0][ci1 * 8]);
    __syncthreads();

    for (int kt = 0; kt <= qt; ++kt) {
        const int cur = kt & 1;
        if (kt < qt) {
            const int kn = kt + 1;
            gload_lds16(kb + (size_t)kn * 4096 + (size_t)kr0 * 64 + sc0, &Kl[cur ^ 1][ci0 * 8]);
            gload_lds16(kb + (size_t)kn * 4096 + (size_t)kr1 * 64 + sc1, &Kl[cur ^ 1][ci1 * 8]);
            gload_lds16(vb + (size_t)kr0 * 2048 + kn * 64 + sc0, &Vl[cur ^ 1][ci0 * 8]);
            gload_lds16(vb + (size_t)kr1 * 2048 + kn * 64 + sc1, &Vl[cur ^ 1][ci1 * 8]);
        }
        const int kbase = kt * 64;
        {
            const __hip_bfloat16* Klb = Kl[cur];
            const __hip_bfloat16* Vlb = Vl[cur];
            f32x4 S[4];
            __builtin_amdgcn_s_setprio(1);
#pragma unroll
            for (int ct = 0; ct < 4; ct++) {
                f32x4 s = {};
                const int r = ct * 16 + r16;
                bf16x8 kf0 = *(const bf16x8*)(Klb + r * 64 + ((kg * 8) ^ swr));
                s = __builtin_amdgcn_mfma_f32_16x16x32_bf16(kf0, qf0, s, 0, 0, 0);
                bf16x8 kf1 = *(const bf16x8*)(Klb + r * 64 + ((32 + kg * 8) ^ swr));
                s = __builtin_amdgcn_mfma_f32_16x16x32_bf16(kf1, qf1, s, 0, 0, 0);
                S[ct] = s;
            }
            __builtin_amdgcn_s_setprio(0);
            if (kbase + 63 > q0) {
#pragma unroll
                for (int ct = 0; ct < 4; ct++)
#pragma unroll
                    for (int j = 0; j < 4; j++)
                        if (kbase + ct * 16 + kg * 4 + j > q0 + r16) S[ct][j] = -3.0e38f;
            }
            float rmax = S[0][0];
#pragma unroll
            for (int ct = 0; ct < 4; ct++)
#pragma unroll
                for (int j = 0; j < 4; j++) rmax = fmaxf(rmax, S[ct][j]);
            rmax = fmaxf(rmax, __shfl_xor(rmax, 16));
            rmax = fmaxf(rmax, __shfl_xor(rmax, 32));
            if (__any(rmax > m_s + 8.0f)) {
                const float mn = fmaxf(m_s, rmax);
                const float al = exp2f(m_s - mn);
                m_s = mn;
                l_s *= al;
#pragma unroll
                for (int j = 0; j < 4; j++) {
                    const float aj = __shfl(al, kg * 4 + j);
#pragma unroll
                    for (int ot = 0; ot < 4; ot++) O[ot][j] *= aj;
                }
            }
            float rsum = 0.f;
#pragma unroll
            for (int ct = 0; ct < 4; ct++)
#pragma unroll
                for (int j = 0; j < 4; j++) { S[ct][j] = exp2f(S[ct][j] - m_s); rsum += S[ct][j]; }
            rsum += __shfl_xor(rsum, 16);
            rsum += __shfl_xor(rsum, 32);
            l_s += rsum;
            bf16x4 pa[4];
#pragma unroll
            for (int ct = 0; ct < 4; ct++) {
                union { __hip_bfloat16 h[4]; bf16x4 v; } pk;
                pk.h[0] = __float2bfloat16(S[ct][0]);
                pk.h[1] = __float2bfloat16(S[ct][1]);
                pk.h[2] = __float2bfloat16(S[ct][2]);
                pk.h[3] = __float2bfloat16(S[ct][3]);
                pa[ct] = pk.v;
            }
            __builtin_amdgcn_s_setprio(1);
#pragma unroll
            for (int ot = 0; ot < 4; ot++) {
                const int vrow = ot * 16 + r16;
#pragma unroll
                for (int ct = 0; ct < 4; ct++) {
                    bf16x4 vf = *(const bf16x4*)(Vlb + vrow * 64 + ((ct * 16 + kg * 4) ^ ((vrow & 7) << 3)));
                    O[ot] = mfma_16x16x16(pa[ct], vf, O[ot]);
                }
            }
            __builtin_amdgcn_s_setprio(0);
        }
        __syncthreads();
    }
    const int b = bh >> 4, h = bh & 15;
    const float linv = 1.0f / l_s;
#pragma unroll
    for (int j = 0; j < 4; j++) {
        const float iv = __shfl(linv, kg * 4 + j);
        const int qq = q0 + kg * 4 + j;
#pragma unroll
        for (int ot = 0; ot < 4; ot++)
            y[((size_t)b * 2048 + qq) * 1024 + h * 64 + ot * 16 + r16] = __float2bfloat16(O[ot][j] * iv);
    }
}

extern "C" void kernel_launch(void* const* d_in, const int* in_sizes, int n_in,
                              void* d_out, int out_size, void* d_ws, size_t ws_size,
                              hipStream_t stream) {
    const float* xp = (const float*)d_in[0];
    const float* Wq = (const float*)d_in[1];
    const float* bq = (const float*)d_in[2];
    const float* Wk = (const float*)d_in[3];
    const float* bk = (const float*)d_in[4];
    const float* Wv = (const float*)d_in[5];
    const float* bv = (const float*)d_in[6];
    const float* Wp = (const float*)d_in[7];
    const float* bp = (const float*)d_in[8];
    float* out = (float*)d_out;

    char* ws = (char*)d_ws;
    __hip_bfloat16* xb     = (__hip_bfloat16*)(ws);                  //  4096*1152 bf16
    __hip_bfloat16* Wqkv_t = (__hip_bfloat16*)(ws + 9437184);        //  3072*1152 bf16 (B^T)
    __hip_bfloat16* Wp_t   = (__hip_bfloat16*)(ws + 16515072);       //  1024*1024 bf16 (B^T)
    __hip_bfloat16* qb     = (__hip_bfloat16*)(ws + 18612224);       //  [32][2048][64]
    __hip_bfloat16* kbv    = (__hip_bfloat16*)(ws + 27000832);       //  [32][2048][64]
    __hip_bfloat16* vtb    = (__hip_bfloat16*)(ws + 35389440);       //  [32][64][2048] (V^T)
    __hip_bfloat16* yb     = (__hip_bfloat16*)(ws + 43778048);       //  [4096][1024]

    k_cvt_bf16<<<2304, 256, 0, stream>>>(xp, xb, 589824);
    dim3 trg4(1024 / 32, 1152 / 32, 4);
    k_tr4<<<trg4, 256, 0, stream>>>(Wq, Wk, Wv, Wp, Wqkv_t, Wp_t);

    dim3 g1(4096 / 128, 3072 / 64);   // 32 x 48 = 1536 blocks = 6/CU
    k_gemmQKV<<<g1, 256, 0, stream>>>(xb, Wqkv_t, 1152, bq, bk, bv, qb, kbv, vtb);
    k_attn<<<1024, 256, 0, stream>>>(qb, kbv, vtb, yb);
    dim3 gp(4096 / 128, 1024 / 64);
    k_gemmP<<<gp, 256, 0, stream>>>(yb, Wp_t, 1024, 1024, bp, out);
}

// Round 15
// 127.640 us; speedup vs baseline: 1.1036x; 1.1036x over previous
//
#include <hip/hip_runtime.h>
#include <hip/hip_bf16.h>

typedef __attribute__((ext_vector_type(8))) short bf16x8;
typedef __attribute__((ext_vector_type(4))) short bf16x4;
typedef __attribute__((ext_vector_type(4))) float f32x4;
typedef __attribute__((ext_vector_type(2))) unsigned int u32x2;

__device__ __forceinline__ void gload_lds16(const void* g, void* l) {
    __builtin_amdgcn_global_load_lds(
        (const __attribute__((address_space(1))) unsigned int*)g,
        (__attribute__((address_space(3))) unsigned int*)l, 16, 0, 0);
}

__device__ __forceinline__ unsigned int pk2(float x, float y) {
    union { __hip_bfloat16 h[2]; unsigned int u; } z;
    z.h[0] = __float2bfloat16(x); z.h[1] = __float2bfloat16(y);
    return z.u;
}

// 16x16x16 bf16 MFMA (HW-verified round 6)
__device__ __forceinline__ f32x4 mfma_16x16x16(bf16x4 a, bf16x4 b, f32x4 c) {
#if __has_builtin(__builtin_amdgcn_mfma_f32_16x16x16bf16_1k)
    return __builtin_amdgcn_mfma_f32_16x16x16bf16_1k(a, b, c, 0, 0, 0);
#else
    f32x4 d = c;
    asm volatile("v_mfma_f32_16x16x16_bf16 %0, %1, %2, %0" : "+v"(d) : "v"(a), "v"(b));
    return d;
#endif
}

// ---------------- fused prep: z=0 cvt xp->bf16 (2 chunks/block); z=1..3 Wq/Wk/Wv^T; z=4 Wp^T ----------------
__global__ void k_prep(const float* __restrict__ xp,
                       const float* __restrict__ Wq, const float* __restrict__ Wk,
                       const float* __restrict__ Wv, const float* __restrict__ Wp,
                       __hip_bfloat16* __restrict__ xb,
                       __hip_bfloat16* __restrict__ Wqkv_t, __hip_bfloat16* __restrict__ Wp_t) {
    __shared__ float tile[32][33];
    const int z = blockIdx.z;
    if (z == 0) {
        // convert 4096*1152 fp32 -> bf16; 1152 blocks x 2 virtual chunks x 2048 elems
        const int lin = blockIdx.y * 32 + blockIdx.x;
#pragma unroll
        for (int r = 0; r < 2; ++r) {
            const size_t e = ((size_t)(lin * 2 + r) * 256 + threadIdx.x) * 8;
            const float4* xp4 = (const float4*)(xp + e);
            float4 a = xp4[0], b = xp4[1];
            union { __hip_bfloat16 h[8]; uint4 u; } tu;
            tu.h[0] = __float2bfloat16(a.x); tu.h[1] = __float2bfloat16(a.y);
            tu.h[2] = __float2bfloat16(a.z); tu.h[3] = __float2bfloat16(a.w);
            tu.h[4] = __float2bfloat16(b.x); tu.h[5] = __float2bfloat16(b.y);
            tu.h[6] = __float2bfloat16(b.z); tu.h[7] = __float2bfloat16(b.w);
            *(uint4*)(xb + e) = tu.u;
        }
        return;
    }
    const int K = (z == 4) ? 1024 : 1152;
    const int N = 1024;
    const int n0 = blockIdx.x * 32, k0 = blockIdx.y * 32;
    if (k0 >= K) return;
    const float* src = (z == 1) ? Wq : ((z == 2) ? Wk : ((z == 3) ? Wv : Wp));
    __hip_bfloat16* d = (z == 4) ? Wp_t : (Wqkv_t + (size_t)(z - 1) * N * 1152);
    const int tx = threadIdx.x & 31, ty = threadIdx.x >> 5;
#pragma unroll
    for (int i = 0; i < 4; i++)
        tile[ty + i * 8][tx] = src[(size_t)(k0 + ty + i * 8) * N + n0 + tx];
    __syncthreads();
#pragma unroll
    for (int i = 0; i < 4; i++)
        d[(size_t)(n0 + ty + i * 8) * K + k0 + tx] = __float2bfloat16(tile[tx][ty + i * 8]);
}

// ---------------- QKV GEMM (round-9/12 proven): 128x128 tile, natural 2D grid ----------------
#define QSCALE 0.18033688011111204f  /* (1/8) * log2(e) */

__global__ __launch_bounds__(256, 2) void k_gemmQKV(
    const __hip_bfloat16* __restrict__ A, const __hip_bfloat16* __restrict__ Bt, int K,
    const float* __restrict__ b0, const float* __restrict__ b1, const float* __restrict__ b2,
    __hip_bfloat16* __restrict__ qb, __hip_bfloat16* __restrict__ kb, __hip_bfloat16* __restrict__ vb)
{
    __shared__ __align__(16) __hip_bfloat16 Sh[16384];
    __hip_bfloat16* As = Sh;
    __hip_bfloat16* Bs = Sh + 8192;
    const int t = threadIdx.x;
    const int lane = t & 63, w = t >> 6;
    const int wr = w >> 1, wc = w & 1;
    const int r16 = lane & 15, kg = lane >> 4;
    const int m0 = blockIdx.x * 128, n0 = blockIdx.y * 128;
    f32x4 acc[4][4] = {};
    const int ksteps = K >> 6;
    for (int kt = 0; kt < ksteps; ++kt) {
        if (kt) __syncthreads();
        const int ks = kt * 64;
#pragma unroll
        for (int i2 = 0; i2 < 4; i2++) {
            int ci = i2 * 256 + t;
            int row = ci >> 3, kc = (ci & 7) * 8;
            gload_lds16(A + (size_t)(m0 + row) * K + ks + kc, As + ci * 8);
        }
#pragma unroll
        for (int i2 = 0; i2 < 4; i2++) {
            int ci = i2 * 256 + t;
            int row = ci >> 3, kc = (ci & 7) * 8;
            gload_lds16(Bt + (size_t)(n0 + row) * K + ks + kc, Bs + ci * 8);
        }
        __syncthreads();
#pragma unroll
        for (int c = 0; c < 2; c++) {
            bf16x8 af[4], bfr[4];
#pragma unroll
            for (int mi = 0; mi < 4; mi++)
                af[mi] = *(const bf16x8*)(As + (wr * 64 + mi * 16 + r16) * 64 + c * 32 + kg * 8);
#pragma unroll
            for (int ni = 0; ni < 4; ni++)
                bfr[ni] = *(const bf16x8*)(Bs + (wc * 64 + ni * 16 + r16) * 64 + c * 32 + kg * 8);
#pragma unroll
            for (int mi = 0; mi < 4; mi++)
#pragma unroll
                for (int ni = 0; ni < 4; ni++)
                    acc[mi][ni] = __builtin_amdgcn_mfma_f32_16x16x32_bf16(af[mi], bfr[ni], acc[mi][ni], 0, 0, 0);
        }
    }
    if (n0 >= 2048) {
        __syncthreads();
#pragma unroll
        for (int mi = 0; mi < 4; mi++) {
#pragma unroll
            for (int ni = 0; ni < 4; ni++) {
                const int nl2 = wc * 64 + ni * 16 + r16;
                const int mb = wr * 64 + mi * 16 + kg * 4;
                const int r = n0 - 2048 + nl2;
                const float bias = b2[r];
                u32x2 pk;
                pk[0] = pk2(acc[mi][ni][0] + bias, acc[mi][ni][1] + bias);
                pk[1] = pk2(acc[mi][ni][2] + bias, acc[mi][ni][3] + bias);
                *(u32x2*)(Sh + nl2 * 128 + (mb ^ ((nl2 & 7) << 3))) = pk;
            }
        }
        __syncthreads();
#pragma unroll
        for (int pass = 0; pass < 8; ++pass) {
            const int ci = pass * 256 + t;
            const int nl2 = ci >> 4;
            const int ms = (ci & 15) * 8;
            bf16x8 v = *(const bf16x8*)(Sh + nl2 * 128 + (ms ^ ((nl2 & 7) << 3)));
            const int r = n0 - 2048 + nl2;
            const int hh = r >> 6, dd = r & 63;
            const int m = m0 + ms;
            const int bb = m >> 11, tt = m & 2047;
            *(bf16x8*)(vb + ((size_t)(bb * 16 + hh) * 64 + dd) * 2048 + tt) = v;
        }
        return;
    }
#pragma unroll
    for (int mi = 0; mi < 4; mi++) {
#pragma unroll
        for (int ni = 0; ni < 4; ni++) {
#pragma unroll
            for (int j = 0; j < 4; j++) {
                int m = m0 + wr * 64 + mi * 16 + kg * 4 + j;
                int n = n0 + wc * 64 + ni * 16 + r16;
                float val = acc[mi][ni][j];
                int r = n & 1023;
                int hh = r >> 6, dd = r & 63;
                int bb = m >> 11, tt = m & 2047;
                if (n < 1024) {
                    val = (val + b0[r]) * QSCALE;
                    qb[((size_t)(bb * 16 + hh) * 2048 + tt) * 64 + dd] = __float2bfloat16(val);
                } else {
                    val += b1[r];
                    kb[((size_t)(bb * 16 + hh) * 2048 + tt) * 64 + dd] = __float2bfloat16(val);
                }
            }
        }
    }
}

// ---------------- proj GEMM: 128x64 tile, 512 blocks (round-12 proven) ----------------
__global__ __launch_bounds__(256, 4) void k_gemmP(
    const __hip_bfloat16* __restrict__ A, const __hip_bfloat16* __restrict__ Bt,
    int N, int K, const float* __restrict__ bias, float* __restrict__ outp)
{
    __shared__ __align__(16) __hip_bfloat16 As[128 * 64];
    __shared__ __align__(16) __hip_bfloat16 Bs[64 * 64];
    const int t = threadIdx.x;
    const int lane = t & 63, w = t >> 6;
    const int wr = w >> 1, wc = w & 1;
    const int r16 = lane & 15, kg = lane >> 4;
    const int m0 = blockIdx.x * 128, n0 = blockIdx.y * 64;
    f32x4 acc[4][2] = {};
    const int ksteps = K >> 6;
    for (int kt = 0; kt < ksteps; ++kt) {
        if (kt) __syncthreads();
        const int ks = kt * 64;
#pragma unroll
        for (int i = 0; i < 4; i++) {
            int ci = i * 256 + t;
            int row = ci >> 3, kc = (ci & 7) * 8;
            gload_lds16(A + (size_t)(m0 + row) * K + ks + kc, As + ci * 8);
        }
#pragma unroll
        for (int i = 0; i < 2; i++) {
            int ci = i * 256 + t;
            int row = ci >> 3, kc = (ci & 7) * 8;
            gload_lds16(Bt + (size_t)(n0 + row) * K + ks + kc, Bs + ci * 8);
        }
        __syncthreads();
#pragma unroll
        for (int c = 0; c < 2; c++) {
            bf16x8 af[4], bfr[2];
#pragma unroll
            for (int mi = 0; mi < 4; mi++)
                af[mi] = *(const bf16x8*)(As + (wr * 64 + mi * 16 + r16) * 64 + c * 32 + kg * 8);
#pragma unroll
            for (int ni = 0; ni < 2; ni++)
                bfr[ni] = *(const bf16x8*)(Bs + (wc * 32 + ni * 16 + r16) * 64 + c * 32 + kg * 8);
#pragma unroll
            for (int mi = 0; mi < 4; mi++)
#pragma unroll
                for (int ni = 0; ni < 2; ni++)
                    acc[mi][ni] = __builtin_amdgcn_mfma_f32_16x16x32_bf16(af[mi], bfr[ni], acc[mi][ni], 0, 0, 0);
        }
    }
#pragma unroll
    for (int mi = 0; mi < 4; mi++)
#pragma unroll
        for (int ni = 0; ni < 2; ni++)
#pragma unroll
            for (int j = 0; j < 4; j++) {
                int m = m0 + wr * 64 + mi * 16 + kg * 4 + j;
                int n = n0 + wc * 32 + ni * 16 + r16;
                outp[(size_t)m * N + n] = acc[mi][ni][j] + bias[n];
            }
}

// ---------------- flash attention (round-12 proven): v6 core + bh->XCD remap ----------------
__global__ __launch_bounds__(256, 4) void k_attn(
    const __hip_bfloat16* __restrict__ qbuf,
    const __hip_bfloat16* __restrict__ kbuf,
    const __hip_bfloat16* __restrict__ vtbuf,
    __hip_bfloat16* __restrict__ y)
{
    __shared__ __align__(16) __hip_bfloat16 Kl[2][64 * 64];
    __shared__ __align__(16) __hip_bfloat16 Vl[2][64 * 64];
    const int t = threadIdx.x, lane = t & 63, w = t >> 6;
    const int r16 = lane & 15, kg = lane >> 4;
    const int g = blockIdx.x;
    const int xcd = g & 7, idx = g >> 3;
    const int j4 = idx >> 5, rr = idx & 31;
    const int bh = xcd * 4 + j4;
    const int qt = (j4 & 1) ? rr : 31 - rr;
    const int swr = (r16 & 7) << 3;
    const int q0 = qt * 64 + w * 16;
    const __hip_bfloat16* qp = qbuf + ((size_t)bh * 2048 + q0) * 64;
    bf16x8 qf0 = *(const bf16x8*)(qp + r16 * 64 + kg * 8);
    bf16x8 qf1 = *(const bf16x8*)(qp + r16 * 64 + 32 + kg * 8);
    f32x4 O[4] = {};
    float m_s = -3.0e38f, l_s = 0.f;
    const __hip_bfloat16* kb = kbuf + (size_t)bh * 2048 * 64;
    const __hip_bfloat16* vb = vtbuf + (size_t)bh * 64 * 2048;

    const int ci0 = t, ci1 = 256 + t;
    const int kr0 = ci0 >> 3, sc0 = ((ci0 & 7) * 8) ^ ((kr0 & 7) << 3);
    const int kr1 = ci1 >> 3, sc1 = ((ci1 & 7) * 8) ^ ((kr1 & 7) << 3);

    gload_lds16(kb + (size_t)kr0 * 64 + sc0, &Kl[0][ci0 * 8]);
    gload_lds16(kb + (size_t)kr1 * 64 + sc1, &Kl[0][ci1 * 8]);
    gload_lds16(vb + (size_t)kr0 * 2048 + sc0, &Vl[0][ci0 * 8]);
    gload_lds16(vb + (size_t)kr1 * 2048 + sc1, &Vl[0][ci1 * 8]);
    __syncthreads();

    for (int kt = 0; kt <= qt; ++kt) {
        const int cur = kt & 1;
        if (kt < qt) {
            const int kn = kt + 1;
            gload_lds16(kb + (size_t)kn * 4096 + (size_t)kr0 * 64 + sc0, &Kl[cur ^ 1][ci0 * 8]);
            gload_lds16(kb + (size_t)kn * 4096 + (size_t)kr1 * 64 + sc1, &Kl[cur ^ 1][ci1 * 8]);
            gload_lds16(vb + (size_t)kr0 * 2048 + kn * 64 + sc0, &Vl[cur ^ 1][ci0 * 8]);
            gload_lds16(vb + (size_t)kr1 * 2048 + kn * 64 + sc1, &Vl[cur ^ 1][ci1 * 8]);
        }
        const int kbase = kt * 64;
        {
            const __hip_bfloat16* Klb = Kl[cur];
            const __hip_bfloat16* Vlb = Vl[cur];
            f32x4 S[4];
            __builtin_amdgcn_s_setprio(1);
#pragma unroll
            for (int ct = 0; ct < 4; ct++) {
                f32x4 s = {};
                const int r = ct * 16 + r16;
                bf16x8 kf0 = *(const bf16x8*)(Klb + r * 64 + ((kg * 8) ^ swr));
                s = __builtin_amdgcn_mfma_f32_16x16x32_bf16(kf0, qf0, s, 0, 0, 0);
                bf16x8 kf1 = *(const bf16x8*)(Klb + r * 64 + ((32 + kg * 8) ^ swr));
                s = __builtin_amdgcn_mfma_f32_16x16x32_bf16(kf1, qf1, s, 0, 0, 0);
                S[ct] = s;
            }
            __builtin_amdgcn_s_setprio(0);
            if (kbase + 63 > q0) {
#pragma unroll
                for (int ct = 0; ct < 4; ct++)
#pragma unroll
                    for (int j = 0; j < 4; j++)
                        if (kbase + ct * 16 + kg * 4 + j > q0 + r16) S[ct][j] = -3.0e38f;
            }
            float rmax = S[0][0];
#pragma unroll
            for (int ct = 0; ct < 4; ct++)
#pragma unroll
                for (int j = 0; j < 4; j++) rmax = fmaxf(rmax, S[ct][j]);
            rmax = fmaxf(rmax, __shfl_xor(rmax, 16));
            rmax = fmaxf(rmax, __shfl_xor(rmax, 32));
            if (__any(rmax > m_s + 8.0f)) {
                const float mn = fmaxf(m_s, rmax);
                const float al = exp2f(m_s - mn);
                m_s = mn;
                l_s *= al;
#pragma unroll
                for (int j = 0; j < 4; j++) {
                    const float aj = __shfl(al, kg * 4 + j);
#pragma unroll
                    for (int ot = 0; ot < 4; ot++) O[ot][j] *= aj;
                }
            }
            float rsum = 0.f;
#pragma unroll
            for (int ct = 0; ct < 4; ct++)
#pragma unroll
                for (int j = 0; j < 4; j++) { S[ct][j] = exp2f(S[ct][j] - m_s); rsum += S[ct][j]; }
            rsum += __shfl_xor(rsum, 16);
            rsum += __shfl_xor(rsum, 32);
            l_s += rsum;
            bf16x4 pa[4];
#pragma unroll
            for (int ct = 0; ct < 4; ct++) {
                union { __hip_bfloat16 h[4]; bf16x4 v; } pk;
                pk.h[0] = __float2bfloat16(S[ct][0]);
                pk.h[1] = __float2bfloat16(S[ct][1]);
                pk.h[2] = __float2bfloat16(S[ct][2]);
                pk.h[3] = __float2bfloat16(S[ct][3]);
                pa[ct] = pk.v;
            }
            __builtin_amdgcn_s_setprio(1);
#pragma unroll
            for (int ot = 0; ot < 4; ot++) {
                const int vrow = ot * 16 + r16;
#pragma unroll
                for (int ct = 0; ct < 4; ct++) {
                    bf16x4 vf = *(const bf16x4*)(Vlb + vrow * 64 + ((ct * 16 + kg * 4) ^ ((vrow & 7) << 3)));
                    O[ot] = mfma_16x16x16(pa[ct], vf, O[ot]);
                }
            }
            __builtin_amdgcn_s_setprio(0);
        }
        __syncthreads();
    }
    const int b = bh >> 4, h = bh & 15;
    const float linv = 1.0f / l_s;
#pragma unroll
    for (int j = 0; j < 4; j++) {
        const float iv = __shfl(linv, kg * 4 + j);
        const int qq = q0 + kg * 4 + j;
#pragma unroll
        for (int ot = 0; ot < 4; ot++)
            y[((size_t)b * 2048 + qq) * 1024 + h * 64 + ot * 16 + r16] = __float2bfloat16(O[ot][j] * iv);
    }
}

extern "C" void kernel_launch(void* const* d_in, const int* in_sizes, int n_in,
                              void* d_out, int out_size, void* d_ws, size_t ws_size,
                              hipStream_t stream) {
    const float* xp = (const float*)d_in[0];
    const float* Wq = (const float*)d_in[1];
    const float* bq = (const float*)d_in[2];
    const float* Wk = (const float*)d_in[3];
    const float* bk = (const float*)d_in[4];
    const float* Wv = (const float*)d_in[5];
    const float* bv = (const float*)d_in[6];
    const float* Wp = (const float*)d_in[7];
    const float* bp = (const float*)d_in[8];
    float* out = (float*)d_out;

    char* ws = (char*)d_ws;
    __hip_bfloat16* xb     = (__hip_bfloat16*)(ws);                  //  4096*1152 bf16
    __hip_bfloat16* Wqkv_t = (__hip_bfloat16*)(ws + 9437184);        //  3072*1152 bf16 (B^T)
    __hip_bfloat16* Wp_t   = (__hip_bfloat16*)(ws + 16515072);       //  1024*1024 bf16 (B^T)
    __hip_bfloat16* qb     = (__hip_bfloat16*)(ws + 18612224);       //  [32][2048][64]
    __hip_bfloat16* kbv    = (__hip_bfloat16*)(ws + 27000832);       //  [32][2048][64]
    __hip_bfloat16* vtb    = (__hip_bfloat16*)(ws + 35389440);       //  [32][64][2048] (V^T)
    __hip_bfloat16* yb     = (__hip_bfloat16*)(ws + 43778048);       //  [4096][1024]

    dim3 gprep(32, 36, 5);
    k_prep<<<gprep, 256, 0, stream>>>(xp, Wq, Wk, Wv, Wp, xb, Wqkv_t, Wp_t);

    dim3 g1(4096 / 128, 3072 / 128);
    k_gemmQKV<<<g1, 256, 0, stream>>>(xb, Wqkv_t, 1152, bq, bk, bv, qb, kbv, vtb);
    k_attn<<<1024, 256, 0, stream>>>(qb, kbv, vtb, yb);
    dim3 gp(4096 / 128, 1024 / 64);
    k_gemmP<<<gp, 256, 0, stream>>>(yb, Wp_t, 1024, 1024, bp, out);
}